// Round 8
// baseline (119.901 us; speedup 1.0000x reference)
//
#include <hip/hip_runtime.h>

// 3x3 conv, stride 1, pad 1, 4096x4096 fp32.
// Block = 256 threads covering a 2048-col x 16-row stripe, walked in 4 steps
// of 4 output rows. Each thread: 8 cols (two float4) x 16 rows. Register
// rotation for the 2 overlapping rows, prefetch distance 2, NT stores.
// R8 change: CPT 4->8 halves per-byte VALU/VMEM overhead (edge loads,
// rotation movs, store count) and doubles bytes in flight per wave.

#define H 4096
#define W 4096
#define CPT 8      // cols per thread (two float4)
#define RPT 4      // rows per step
#define STEPS 4    // steps per block (stripe = 16 rows)
#define BLOCK 256

typedef float vfloat4 __attribute__((ext_vector_type(4)));

struct Row {
    vfloat4 a, b;   // cols c..c+3, c+4..c+7
    float lf, rt;   // col c-1, col c+8
};

__device__ __forceinline__ void load_row(const float* __restrict__ x, int rr,
                                         int c, Row& r) {
    if (rr >= 0 && rr < H) {
        const float* row = x + (size_t)rr * W + c;
        r.a = *(const vfloat4*)row;
        r.b = *(const vfloat4*)(row + 4);
        r.lf = (c > 0) ? row[-1] : 0.0f;
        r.rt = (c + CPT < W) ? row[CPT] : 0.0f;
    } else {
        r.a = (vfloat4)(0.f);
        r.b = (vfloat4)(0.f);
        r.lf = 0.f;
        r.rt = 0.f;
    }
}

__global__ __launch_bounds__(BLOCK, 2) void conv3x3_stripe(
    const float* __restrict__ x, const float* __restrict__ w9,
    const float* __restrict__ bias, float* __restrict__ out) {
    const int c = (blockIdx.x * BLOCK + threadIdx.x) * CPT;
    const int rbase = blockIdx.y * (STEPS * RPT);

    float wv[9];
#pragma unroll
    for (int i = 0; i < 9; ++i) wv[i] = w9[i];
    const float b = bias[0];

    // Current window: rows rbase-1 .. rbase+4.
    Row v[6];
#pragma unroll
    for (int i = 0; i < 6; ++i) load_row(x, rbase - 1 + i, c, v[i]);

    // Prefetch stage 1: rows rbase+5 .. rbase+8 (for step 1).
    Row p[4];
#pragma unroll
    for (int k = 0; k < 4; ++k) load_row(x, rbase + 5 + k, c, p[k]);

#pragma unroll
    for (int s = 0; s < STEPS; ++s) {
        const int r0 = rbase + s * RPT;

        // Prefetch stage 2: rows r0+9 .. r0+12 (for step s+2).
        Row q[4];
        if (s < STEPS - 2) {
#pragma unroll
            for (int k = 0; k < 4; ++k) load_row(x, r0 + 9 + k, c, q[k]);
        }

        vfloat4 accA[RPT], accB[RPT];
#pragma unroll
        for (int j = 0; j < RPT; ++j) { accA[j] = (vfloat4)(b); accB[j] = (vfloat4)(b); }

#pragma unroll
        for (int j = 0; j < RPT; ++j) {
#pragma unroll
            for (int dr = 0; dr < 3; ++dr) {
                const Row& r = v[j + dr];
                const float w0 = wv[dr * 3 + 0];
                const float w1 = wv[dr * 3 + 1];
                const float w2 = wv[dr * 3 + 2];
                accA[j].x = fmaf(w0, r.lf,  fmaf(w1, r.a.x, fmaf(w2, r.a.y, accA[j].x)));
                accA[j].y = fmaf(w0, r.a.x, fmaf(w1, r.a.y, fmaf(w2, r.a.z, accA[j].y)));
                accA[j].z = fmaf(w0, r.a.y, fmaf(w1, r.a.z, fmaf(w2, r.a.w, accA[j].z)));
                accA[j].w = fmaf(w0, r.a.z, fmaf(w1, r.a.w, fmaf(w2, r.b.x, accA[j].w)));
                accB[j].x = fmaf(w0, r.a.w, fmaf(w1, r.b.x, fmaf(w2, r.b.y, accB[j].x)));
                accB[j].y = fmaf(w0, r.b.x, fmaf(w1, r.b.y, fmaf(w2, r.b.z, accB[j].y)));
                accB[j].z = fmaf(w0, r.b.y, fmaf(w1, r.b.z, fmaf(w2, r.b.w, accB[j].z)));
                accB[j].w = fmaf(w0, r.b.z, fmaf(w1, r.b.w, fmaf(w2, r.rt,  accB[j].w)));
            }
        }

#pragma unroll
        for (int j = 0; j < RPT; ++j) {
            float* orow = out + (size_t)(r0 + j) * W + c;
            __builtin_nontemporal_store(accA[j], (vfloat4*)orow);
            __builtin_nontemporal_store(accB[j], (vfloat4*)(orow + 4));
        }

        // Rotate window and pipeline stages.
        if (s < STEPS - 1) {
            v[0] = v[4];
            v[1] = v[5];
#pragma unroll
            for (int k = 0; k < 4; ++k) {
                v[2 + k] = p[k];
                p[k] = q[k];
            }
        }
    }
}

extern "C" void kernel_launch(void* const* d_in, const int* in_sizes, int n_in,
                              void* d_out, int out_size, void* d_ws, size_t ws_size,
                              hipStream_t stream) {
    const float* x = (const float*)d_in[0];
    const float* w = (const float*)d_in[1];
    const float* bias = (const float*)d_in[2];
    float* out = (float*)d_out;

    dim3 block(BLOCK, 1, 1);
    dim3 grid(W / (BLOCK * CPT), H / (STEPS * RPT), 1);
    conv3x3_stripe<<<grid, block, 0, stream>>>(x, w, bias, out);
}